// Round 9
// baseline (189.087 us; speedup 1.0000x reference)
//
#include <hip/hip_runtime.h>
#include <math.h>

#define HH 160
#define WW 160
#define HWSZ 25600
#define TR 14
#define TC 22
#define NSLOT 308   // TR*TC tile slots, margin +-3 around 16x8 px tile

typedef __attribute__((ext_vector_type(8))) short short8;
typedef __attribute__((ext_vector_type(4))) short short4v;
typedef __attribute__((ext_vector_type(8))) _Float16 half8;
typedef __attribute__((ext_vector_type(2))) _Float16 half2v;
typedef __attribute__((ext_vector_type(4))) float f32x4;
typedef __attribute__((ext_vector_type(16))) float f32x16;
typedef __attribute__((ext_vector_type(2))) unsigned int uint2v;

__device__ __forceinline__ short f2h(float f) {
  union { _Float16 h; short s; } u; u.h = (_Float16)f; return u.s;
}
__device__ __forceinline__ float h2f(short s) {
  union { _Float16 h; short s; } u; u.s = s; return (float)u.h;
}
__device__ __forceinline__ half2v bcast_h(short s) {
  unsigned int x = (unsigned short)s; x |= x << 16;
  union { unsigned int u; half2v h; } v; v.u = x; return v.h;
}

// ---------------------------------------------------------------------------
// pre: blocks [0,1600): transpose x f32 NCHW -> f16 NHWC.
//      blocks [1600,1664): BN fold + weight reorder to A-frag layouts.
// dcn w (32x32x16 A-frag): [tap9][s4][ot2][hi2][oc32][j8]
//      element (oc_g=ot*32+oc, c=s*16+hi*8+j, tap); lane l reads l*16B
//      contiguous per (s,ot) -> fully coalesced 1KB wave access.
// om  w (32x32x16 A-frag): [kk36=tap*4+s][hi2][oc32][j8], oc>=27 zeroed;
//      same K-order (c=s*16+hi*8+j) so B-frag reads match the main loop.
__global__ __launch_bounds__(256) void pre_kernel(
    const float* __restrict__ x,
    const float* __restrict__ g1, const float* __restrict__ b1,
    const float* __restrict__ m1, const float* __restrict__ v1,
    const float* __restrict__ g2, const float* __restrict__ b2,
    const float* __restrict__ m2, const float* __restrict__ v2,
    const float* __restrict__ wd1, const float* __restrict__ wd2,
    const float* __restrict__ wo1, const float* __restrict__ wo2,
    float* __restrict__ sc, short* __restrict__ wd1h, short* __restrict__ wd2h,
    short* __restrict__ wo1h, short* __restrict__ wo2h,
    short* __restrict__ xcl) {
  __shared__ short tmp[64][72];
  int t = threadIdx.x;
  int bx = blockIdx.x;
  if (bx < 1600) {
    int b = bx / 400, p0 = (bx - b * 400) * 64;
    const float* xb = x + (size_t)b * 64 * HWSZ;
    for (int i = t; i < 4096; i += 256) {
      int c = i >> 6, p = i & 63;
      tmp[p][c] = f2h(xb[c * HWSZ + p0 + p]);
    }
    __syncthreads();
    short* ob = xcl + ((size_t)b * HWSZ + p0) * 64;
    for (int i = t; i < 512; i += 256) {
      int p = i >> 3, g = i & 7;
      *(short8*)&ob[p * 64 + g * 8] = *(const short8*)&tmp[p][g * 8];
    }
    return;
  }
  int i0 = (bx - 1600) * 256 + t;  // 0..16383
  for (int i = i0; i < 36864; i += 16384) {
    int j = i & 7, oc = (i >> 3) & 31, hi = (i >> 8) & 1;
    int ot = (i >> 9) & 1, s = (i >> 10) & 3, tap = i >> 12;
    int src = (ot * 32 + oc) * 576 + (s * 16 + hi * 8 + j) * 9 + tap;
    wd1h[i] = f2h(wd1[src]);
    wd2h[i] = f2h(wd2[src]);
  }
  for (int i = i0; i < 18432; i += 16384) {
    int j = i & 7, oc = (i >> 3) & 31, hi = (i >> 8) & 1;
    int s = (i >> 9) & 3, tap = i >> 11;
    int src = oc * 576 + (s * 16 + hi * 8 + j) * 9 + tap;
    wo1h[i] = (oc < 27) ? f2h(wo1[src]) : (short)0;
    wo2h[i] = (oc < 27) ? f2h(wo2[src]) : (short)0;
  }
  if (i0 < 64) {
    float s1 = g1[i0] * rsqrtf(v1[i0] + 1e-5f);
    sc[i0]       = s1;
    sc[64 + i0]  = b1[i0] - m1[i0] * s1;
    float s2 = g2[i0] * rsqrtf(v2[i0] + 1e-5f);
    sc[128 + i0] = s2;
    sc[192 + i0] = b2[i0] - m2[i0] * s2;
  }
}

// ---------------------------------------------------------------------------
// dcn_fused: offset-conv (27ch) + modulated deform conv (64->64) + BN
//            + optional residual + GELU, all from one staged tile.
// Block: 16x * 8y px, 256 thr / 4 waves, all GEMMs 32x32x16.
// om results land in the consuming lane (D col = px lane); the missing
// oc-half comes from lane^32 via permlane32_swap -- no LDS scratch.
// Main GEMM is a flat 36-step (tap,slice) pipeline: meta for ALL taps
// hoisted to registers first, then each step issues the NEXT step's 4
// corner ds_reads + A-frag global loads before combining the current
// step -> >=1 gather always in flight per wave (deep per-wave ILP; the
// grid caps TLP at ~3 blocks/CU so latency must be hidden in-wave).
// LDS = xt only (39424 B); ONE barrier total.
__global__ __launch_bounds__(256, 3) void dcn_fused(
    const short* __restrict__ xcl,     // [B][HW][64] f16 NHWC
    const short* __restrict__ who,     // om weights  [kk36][hi2][oc32][j8]
    const float* __restrict__ bias_om, // 27
    const short* __restrict__ whd,     // dcn weights [tap][s][ot][hi][oc][j]
    const float* __restrict__ scale, const float* __restrict__ shift,
    const short* __restrict__ id_cl,     // f16 NHWC residual or null
    short* __restrict__ out_cl,          // f16 NHWC (layer 1) or null
    float* __restrict__ out_f32) {       // f32 NCHW (layer 2) or null
  __shared__ short xt[NSLOT * 64];          // 39424 B, 16B groups swizzled

  int t = threadIdx.x;
  int x0 = blockIdx.x * 16, y0 = blockIdx.y * 8, b = blockIdx.z;
  int w = t >> 6, lane = t & 63, m = lane & 15;
  int hi = lane >> 5, p31 = lane & 31;
  int ybase = y0 - 3, xbase = x0 - 3;

  // ---- stage tile (coalesced b128 copies) ----
  const short* xb = xcl + (size_t)b * HWSZ * 64;
  for (int i = t; i < NSLOT * 8; i += 256) {
    int slot = i >> 3, g = i & 7;
    int ty = slot / TC, tx = slot - ty * TC;
    int gy = ybase + ty, gx = xbase + tx;
    short8 v = {};
    if (gy >= 0 && gy < HH && gx >= 0 && gx < WW)
      v = *(const short8*)&xb[(gy * WW + gx) * 64 + g * 8];
    *(short8*)&xt[slot * 64 + ((g ^ (slot & 7)) << 3)] = v;
  }
  __syncthreads();  // xt visible -- the ONLY barrier

  // ---- om GEMM (32x32x16): 27 oc x 32 px per wave, D col = own pixel ----
  union { short s[32]; unsigned int u[16]; } omr;
  {
    f32x16 oacc = {};
#pragma unroll
    for (int k9 = 0; k9 < 9; k9++) {
      int ki = k9 / 3, kj = k9 - ki * 3;
      int slotb = (w * 2 + (p31 >> 4) + ki + 2) * TC + ((p31 & 15) + kj + 2);
#pragma unroll
      for (int s = 0; s < 4; s++) {
        int g = s * 2 + hi;
        union { short8 s8; half8 h; } A, B;
        B.s8 = *(const short8*)&xt[slotb * 64 + ((g ^ (slotb & 7)) << 3)];
        A.s8 = *(const short8*)&who[((k9 * 4 + s) * 64 + lane) * 8];
        oacc = __builtin_amdgcn_mfma_f32_32x32x16_f16(A.h, B.h, oacc, 0, 0, 0);
      }
    }
#pragma unroll
    for (int j = 0; j < 8; j++) {
      int c0 = 2 * (j & 1) + 8 * (j >> 1);  // channel pair base for hi=0
      int oc0 = c0 + 4 * hi;                // this lane's oc for r=2j
      float b0 = (oc0 < 27) ? bias_om[oc0] : 0.f;
      float b1 = (oc0 + 1 < 27) ? bias_om[oc0 + 1] : 0.f;
      union { unsigned int u; short s2[2]; } pk;
      pk.s2[0] = f2h(oacc[2 * j] + b0);
      pk.s2[1] = f2h(oacc[2 * j + 1] + b1);
      uint2v sw = __builtin_amdgcn_permlane32_swap(pk.u, pk.u, false, false);
      omr.u[c0 >> 1]       = sw[0];
      omr.u[(c0 + 4) >> 1] = sw[1];
    }
  }

  int y = y0 + w * 2 + (p31 >> 4), x = x0 + m;

  // ---- hoist ALL taps' sampling meta into registers (verbatim formulas) ----
  half2v wgt[9][4];  // bilinear*mask weights, bcast as f16x2
  int bs[9];         // corner-00 slot index
#pragma unroll
  for (int k = 0; k < 9; ++k) {
    float dy = h2f(omr.s[2 * k]);
    float dx = h2f(omr.s[2 * k + 1]);
    float ml = h2f(omr.s[18 + k]);
    float msk = 1.f / (1.f + __expf(-ml));
    int ki = k / 3, kj = k - ki * 3;
    float py  = (float)(y - 1 + ki) + dy;
    float pxf = (float)(x - 1 + kj) + dx;
    float fy = floorf(py), fx = floorf(pxf);
    float ly = py - fy, lx = pxf - fx;
    int yi0 = (int)fy, xi0 = (int)fx;
    bool vy0 = (yi0 >= 0) & (yi0 < HH), vy1 = (yi0 + 1 >= 0) & (yi0 + 1 < HH);
    bool vx0 = (xi0 >= 0) & (xi0 < WW), vx1 = (xi0 + 1 >= 0) & (xi0 + 1 < WW);
    int ty0 = min(max(yi0 - ybase, 0), TR - 2);
    int tx0 = min(max(xi0 - xbase, 0), TC - 2);
    bs[k] = ty0 * TC + tx0;
    wgt[k][0] = bcast_h(f2h((vy0 & vx0) ? (1.f - ly) * (1.f - lx) * msk : 0.f));
    wgt[k][1] = bcast_h(f2h((vy0 & vx1) ? (1.f - ly) * lx * msk : 0.f));
    wgt[k][2] = bcast_h(f2h((vy1 & vx0) ? ly * (1.f - lx) * msk : 0.f));
    wgt[k][3] = bcast_h(f2h((vy1 & vx1) ? ly * lx * msk : 0.f));
  }

  // ---- main GEMM (32x32x16): flat 36-step (k,s) pipeline, 1-ahead ----
#define CLOAD(dst, kk, ss)                                                   \
  do {                                                                       \
    int g_ = (ss) * 2 + hi;                                                  \
    int p_ = bs[kk];                                                         \
    dst[0] = *(const short8*)&xt[p_ * 64 + ((g_ ^ (p_ & 7)) << 3)];          \
    dst[1] = *(const short8*)&xt[(p_ + 1) * 64 +                             \
                                 ((g_ ^ ((p_ + 1) & 7)) << 3)];              \
    dst[2] = *(const short8*)&xt[(p_ + TC) * 64 +                            \
                                 ((g_ ^ ((p_ + TC) & 7)) << 3)];             \
    dst[3] = *(const short8*)&xt[(p_ + TC + 1) * 64 +                        \
                                 ((g_ ^ ((p_ + TC + 1) & 7)) << 3)];         \
  } while (0)

  f32x16 acc0 = {}, acc1 = {};
  short8 cor[2][4];
  short8 pa0, pa1;
  CLOAD(cor[0], 0, 0);
  pa0 = *(const short8*)&whd[lane * 8];
  pa1 = *(const short8*)&whd[512 + lane * 8];
#pragma unroll
  for (int i = 0; i < 36; ++i) {
    int k = i >> 2;
    int cur = i & 1;
    if (i + 1 < 36) {  // issue next step's 4 corner reads
      int nk = (i + 1) >> 2, ns = (i + 1) & 3;
      CLOAD(cor[cur ^ 1], nk, ns);
    }
    short8 A0 = pa0, A1 = pa1;
    if (i + 1 < 36) {  // issue next step's A-frag global loads
      int nk = (i + 1) >> 2, ns = (i + 1) & 3;
      pa0 = *(const short8*)&whd[nk * 4096 + ns * 1024 + lane * 8];
      pa1 = *(const short8*)&whd[nk * 4096 + ns * 1024 + 512 + lane * 8];
    }
    union { short8 s8; half2v h[4]; } c0, c1, c2, c3, bb;
    c0.s8 = cor[cur][0]; c1.s8 = cor[cur][1];
    c2.s8 = cor[cur][2]; c3.s8 = cor[cur][3];
#pragma unroll
    for (int d = 0; d < 4; d++)
      bb.h[d] = c0.h[d] * wgt[k][0] + c1.h[d] * wgt[k][1] +
                c2.h[d] * wgt[k][2] + c3.h[d] * wgt[k][3];
    union { short8 s8; half8 h8; } B, UA0, UA1;
    B.s8 = bb.s8; UA0.s8 = A0; UA1.s8 = A1;
    acc0 = __builtin_amdgcn_mfma_f32_32x32x16_f16(UA0.h8, B.h8, acc0, 0, 0, 0);
    acc1 = __builtin_amdgcn_mfma_f32_32x32x16_f16(UA1.h8, B.h8, acc1, 0, 0, 0);
  }
#undef CLOAD

  // ---- epilogue ----
  // D layout (32x32): col px = lane&31; row oc_in_tile = (r&3)+8*(r>>2)+4*hi
  if (out_f32) {  // layer 2: BN + residual (f16 NHWC) + GELU -> f32 NCHW
    short4v ivs[8];
    size_t pbase = ((size_t)b * HWSZ + y * WW + x) * 64;
#pragma unroll
    for (int ot = 0; ot < 2; ot++)
#pragma unroll
      for (int blk = 0; blk < 4; blk++)
        ivs[ot * 4 + blk] =
            *(const short4v*)&id_cl[pbase + ot * 32 + blk * 8 + hi * 4];
#pragma unroll
    for (int ot = 0; ot < 2; ot++) {
#pragma unroll
      for (int r = 0; r < 16; r++) {
        int oc = ot * 32 + (r & 3) + 8 * (r >> 2) + 4 * hi;
        float a = ot ? acc1[r] : acc0[r];
        size_t idx = ((size_t)(b * 64 + oc)) * HWSZ + y * WW + x;
        float v = a * scale[oc] + shift[oc] + h2f(ivs[ot * 4 + (r >> 2)][r & 3]);
        v = 0.5f * v * (1.f + erff(v * 0.70710678118654752f));
        out_f32[idx] = v;
      }
    }
  } else {  // layer 1: BN + GELU -> f16 NHWC
    size_t base = ((size_t)b * HWSZ + y * WW + x) * 64;
#pragma unroll
    for (int ot = 0; ot < 2; ot++) {
#pragma unroll
      for (int blk = 0; blk < 4; blk++) {
        short4v pv;
#pragma unroll
        for (int rr = 0; rr < 4; rr++) {
          int r = blk * 4 + rr;
          int oc = ot * 32 + blk * 8 + hi * 4 + rr;
          float a = ot ? acc1[r] : acc0[r];
          float v = a * scale[oc] + shift[oc];
          v = 0.5f * v * (1.f + erff(v * 0.70710678118654752f));
          pv[rr] = f2h(v);
        }
        *(short4v*)&out_cl[base + ot * 32 + blk * 8 + hi * 4] = pv;
      }
    }
  }
}

// ---------------------------------------------------------------------------
extern "C" void kernel_launch(void* const* d_in, const int* in_sizes, int n_in,
                              void* d_out, int out_size, void* d_ws, size_t ws_size,
                              hipStream_t stream) {
  const float* x     = (const float*)d_in[0];
  const float* w_om1 = (const float*)d_in[1];
  const float* b_om1 = (const float*)d_in[2];
  const float* w_d1  = (const float*)d_in[3];
  const float* bn1g  = (const float*)d_in[4];
  const float* bn1b  = (const float*)d_in[5];
  const float* bn1m  = (const float*)d_in[6];
  const float* bn1v  = (const float*)d_in[7];
  const float* w_om2 = (const float*)d_in[8];
  const float* b_om2 = (const float*)d_in[9];
  const float* w_d2  = (const float*)d_in[10];
  const float* bn2g  = (const float*)d_in[11];
  const float* bn2b  = (const float*)d_in[12];
  const float* bn2m  = (const float*)d_in[13];
  const float* bn2v  = (const float*)d_in[14];

  float* ws    = (float*)d_ws;
  float* sc    = ws;                       // 256 f
  short* w1h   = (short*)(ws + 256);       // 36864 halves
  short* w2h   = w1h + 36864;
  short* wo1h  = w2h + 36864;              // 18432 halves
  short* wo2h  = wo1h + 18432;
  short* x_cl  = (short*)(ws + 55552);     // 6,553,600 halves
  short* o1_cl = x_cl + 6553600;           // 6,553,600 halves
  float* outp  = (float*)d_out;

  pre_kernel<<<dim3(1664), dim3(256), 0, stream>>>(
      x, bn1g, bn1b, bn1m, bn1v, bn2g, bn2b, bn2m, bn2v,
      w_d1, w_d2, w_om1, w_om2, sc, w1h, w2h, wo1h, wo2h, x_cl);

  dim3 grid(WW / 16, HH / 8, 4);
  dcn_fused<<<grid, dim3(256), 0, stream>>>(
      x_cl, wo1h, b_om1, w1h, sc, sc + 64, nullptr, o1_cl, nullptr);
  dcn_fused<<<grid, dim3(256), 0, stream>>>(
      o1_cl, wo2h, b_om2, w2h, sc + 128, sc + 192, x_cl, nullptr, outp);
}